// Round 12
// baseline (43.579 us; speedup 1.0000x reference)
//
#include <hip/hip_runtime.h>

typedef _Float16 h16;
typedef __attribute__((ext_vector_type(2))) h16 h2v;
typedef __attribute__((ext_vector_type(8))) h16 h8v;

constexpr int H_ = 60, W_ = 108, HW_ = 6480;

// Workspace byte offsets. Features position-major [pos][128] fp16 (256 B/row).
// All features pre-scaled by 128^-0.25 so every dot carries 1/sqrt(128).
// L2 and L3 of each map are CONTIGUOUS (L3 = L2 + 103680).
constexpr unsigned B_F0T  = 0;
constexpr unsigned B_F1T  = 1658880;
constexpr unsigned B_F0L1 = 3317760;   // 30*54
constexpr unsigned B_F0L2 = 3732480;   // 15*27
constexpr unsigned B_F0L3 = 3836160;   // 7*13  (= B_F0L2 + 103680)
constexpr unsigned B_F1L1 = 3859456;
constexpr unsigned B_F1L2 = 4274176;
constexpr unsigned B_F1L3 = 4377856;   // (= B_F1L2 + 103680)

constexpr int ROW_L3  = 405;           // lvl3 starts at region-row 405
constexpr unsigned LDS_TOT = 126976;   // staged lvl2+lvl3 (496 rows x 256 B)

// ---------------------------------------------------------------------------
// Transpose [128][6480] f32 -> [6480][128] f16 (pre-scaled), both maps.
__global__ __launch_bounds__(256) void k_transpose(const float* __restrict__ f0,
                                                   const float* __restrict__ f1,
                                                   h16* __restrict__ ws) {
    __shared__ float lds[64 * 129];
    const float* src = blockIdx.y ? f1 : f0;
    h16* dst = (h16*)((char*)ws + (blockIdx.y ? B_F1T : B_F0T));
    const int p0 = blockIdx.x * 64;
    const int t  = threadIdx.x;
    const int pr = t & 63, cr = t >> 6;
    #pragma unroll
    for (int cb = 0; cb < 128; cb += 4) {
        int c = cb + cr, p = p0 + pr;
        if (p < HW_) lds[pr * 129 + c] = src[(size_t)c * HW_ + p];
    }
    __syncthreads();
    const float S = 0.29730177875068026f;   // 128^-0.25
    const int cw = t & 63, pw = t >> 6;     // cw indexes half2 pairs
    #pragma unroll
    for (int pb = 0; pb < 64; pb += 4) {
        int p = p0 + pb + pw;
        if (p < HW_) {
            float a = lds[(pb + pw) * 129 + 2 * cw] * S;
            float b = lds[(pb + pw) * 129 + 2 * cw + 1] * S;
            h2v v; v.x = (h16)a; v.y = (h16)b;
            ((h2v*)dst)[(size_t)p * 64 + cw] = v;
        }
    }
}

// ---------------------------------------------------------------------------
// Full pyramid in ONE launch. L1 = 2x2 avg; L2 = direct 4x4 of L0; L3 =
// direct 8x8 of L0 (identical to iterated 2x2 under floor semantics).
__global__ __launch_bounds__(256) void k_pyramid(h16* __restrict__ wsh) {
    char* ws = (char*)wsh;
    const int map = blockIdx.y;
    const char* s = ws + (map ? B_F1T : B_F0T);
    const int bid = blockIdx.x;
    const int t = threadIdx.x;

    if (bid < 102) {                    // ---- L1: 2x2, 1620 pos x 16 chunks
        const int idx = bid * 256 + t;
        if (idx >= 1620 * 16) return;
        const int pos = idx >> 4, q = idx & 15;
        const int y = pos / 54, x = pos - y * 54;
        const unsigned r0 = (unsigned)(2 * y * 108 + 2 * x) * 256 + q * 16;
        const unsigned r1 = r0 + 108 * 256;
        h8v a = *(const h8v*)(s + r0);
        h8v b = *(const h8v*)(s + r0 + 256);
        h8v c = *(const h8v*)(s + r1);
        h8v d = *(const h8v*)(s + r1 + 256);
        h8v o;
        #pragma unroll
        for (int k = 0; k < 8; ++k)
            o[k] = (h16)((((float)a[k] + (float)b[k]) + ((float)c[k] + (float)d[k])) * 0.25f);
        *(h8v*)(ws + (map ? B_F1L1 : B_F0L1) + (unsigned)pos * 256 + q * 16) = o;
    } else if (bid < 128) {             // ---- L2: direct 4x4, 405 pos x 16
        const int idx = (bid - 102) * 256 + t;
        if (idx >= 405 * 16) return;
        const int pos = idx >> 4, q = idx & 15;
        const int y = pos / 27, x = pos - y * 27;
        float acc[8] = {};
        #pragma unroll
        for (int dy = 0; dy < 4; ++dy) {
            #pragma unroll
            for (int dx = 0; dx < 4; ++dx) {
                h8v u = *(const h8v*)(s + (unsigned)((4 * y + dy) * 108 + 4 * x + dx) * 256 + q * 16);
                #pragma unroll
                for (int k = 0; k < 8; ++k) acc[k] += (float)u[k];
            }
        }
        h8v o;
        #pragma unroll
        for (int k = 0; k < 8; ++k) o[k] = (h16)(acc[k] * 0.0625f);
        *(h8v*)(ws + (map ? B_F1L2 : B_F0L2) + (unsigned)pos * 256 + q * 16) = o;
    } else {                            // ---- L3: direct 8x8, 1 wave per (pos, half)
        const int idx = (bid - 128) * 256 + t;
        if (idx >= 91 * 128) return;
        const int pos = idx >> 7;
        const int sub = idx & 127;
        const int half = sub >> 6, lane = sub & 63;
        const int j = lane >> 3, qq = (lane & 7) + half * 8;  // row j, chunk qq
        const int y = pos / 13, x = pos - y * 13;
        float acc[8] = {};
        #pragma unroll
        for (int dx = 0; dx < 8; ++dx) {
            h8v u = *(const h8v*)(s + (unsigned)((8 * y + j) * 108 + 8 * x + dx) * 256 + qq * 16);
            #pragma unroll
            for (int k = 0; k < 8; ++k) acc[k] += (float)u[k];
        }
        #pragma unroll
        for (int k = 0; k < 8; ++k) {   // reduce over rows j (lane bits 3..5)
            acc[k] += __shfl_xor(acc[k], 8);
            acc[k] += __shfl_xor(acc[k], 16);
            acc[k] += __shfl_xor(acc[k], 32);
        }
        if (j == 0) {
            h8v o;
            #pragma unroll
            for (int k = 0; k < 8; ++k) o[k] = (h16)(acc[k] * 0.015625f);
            *(h8v*)(ws + (map ? B_F1L3 : B_F0L3) + (unsigned)pos * 256 + qq * 16) = o;
        }
    }
}

// ---------------------------------------------------------------------------
template <int CTRL>
__device__ __forceinline__ float dpp_add(float x) {
    int y = __builtin_amdgcn_update_dpp(0, __builtin_bit_cast(int, x),
                                        CTRL, 0xF, 0xF, true);
    return x + __builtin_bit_cast(float, y);
}

__device__ __forceinline__ float dot_u4(uint4 u, uint4 s, float acc) {
    acc = __builtin_amdgcn_fdot2(__builtin_bit_cast(h2v, u.x),
                                 __builtin_bit_cast(h2v, s.x), acc, false);
    acc = __builtin_amdgcn_fdot2(__builtin_bit_cast(h2v, u.y),
                                 __builtin_bit_cast(h2v, s.y), acc, false);
    acc = __builtin_amdgcn_fdot2(__builtin_bit_cast(h2v, u.z),
                                 __builtin_bit_cast(h2v, s.z), acc, false);
    acc = __builtin_amdgcn_fdot2(__builtin_bit_cast(h2v, u.w),
                                 __builtin_bit_cast(h2v, s.w), acc, false);
    return acc;
}

// ---------------------------------------------------------------------------
// Persistent lookup v4: as v3 (256 blocks x 1024 thr, lvl2+3 staged in LDS),
// but the staged layout is XOR-SWIZZLED: chunk cir of region-row R lives at
// (cir&8)|((cir^R)&7). The gather read (8 lanes sharing ch across consecutive
// rows) then covers all 32 banks uniformly -> conflict-free ds_read_b128
// (was an 8-way conflict: all rows alias bank group 4*ch).
__global__ __launch_bounds__(1024, 1) void k_lookup4(const h16* __restrict__ wsh,
                                                     const float* __restrict__ flow0,
                                                     const float* __restrict__ flow1,
                                                     const float* __restrict__ embt,
                                                     float* __restrict__ out) {
    extern __shared__ char lds2[];
    const char* ws = (const char*)wsh;
    const int bid = blockIdx.x;
    const int xcd = bid & 7;
    const int dir = xcd >> 2;                        // XCDs 0-3: dir0, 4-7: dir1
    const int dirblk = (bid >> 3) * 4 + (xcd & 3);   // 0..127 within dir
    const int t = threadIdx.x;
    const int L = t & 63;
    const int wv = t >> 6;                           // 0..15

    // stage lvl2+lvl3 (7936 uint4), SWIZZLED: chunk c -> row R=c>>4,
    // cir=c&15 stored at (cir&8)|((cir^R)&7)
    {
        const uint4* src = (const uint4*)(ws + (dir ? B_F0L2 : B_F1L2));
        #pragma unroll
        for (int i = 0; i < 8; ++i) {
            const int c = t + i * 1024;
            if (c < 7936) {
                const int R = c >> 4, cir = c & 15;
                const int cs = (cir & 8) | ((cir ^ R) & 7);
                ((uint4*)lds2)[(R << 4) | cs] = src[c];
            }
        }
    }

    const int rbeg = (dirblk * 6480) >> 7;           // pixel range of this block
    const int rend = ((dirblk + 1) * 6480) >> 7;
    const int npix = rend - rbeg;                    // 50 or 51

    const float e = embt[0];
    const float scale = dir ? 1.0f / (1.0f - e) : 1.0f / e;
    const float* fl = dir ? flow0 : flow1;
    const unsigned sB  = dir ? B_F1T : B_F0T;    // source features (own map)
    const unsigned gB0 = dir ? B_F0T : B_F1T;    // gather lvl0
    const unsigned gB1 = dir ? B_F0L1 : B_F1L1;  // gather lvl1

    const int ch = L & 7;        // 16B chunk index
    const int p  = L >> 3;       // window column 0..7

    __syncthreads();             // staged lvl2/3 ready

    float vals[4][4];            // [pass][lvl]

    #pragma unroll
    for (int ps = 0; ps < 4; ++ps) {
        const int lpix = ps * 16 + wv;       // block-local pixel index
        const int pix = rbeg + lpix;
        const bool act = (lpix < npix);

        if (act) {
            const int hh = pix / 108, ww = pix - hh * 108;
            const float cx = (float)ww + fl[pix] * scale;
            const float cy = (float)hh + fl[HW_ + pix] * scale;
            const unsigned sbase = sB + (unsigned)pix * 256;
            const uint4 su0 = *(const uint4*)(ws + sbase + ch * 16);
            const uint4 su1 = *(const uint4*)(ws + sbase + 128 + ch * 16);

            #pragma unroll
            for (int lvl = 0; lvl < 4; ++lvl) {
                const int wl = 108 >> lvl, hl = 60 >> lvl;
                const float inv = (lvl == 0) ? 1.f : (lvl == 1) ? 0.5f
                                : (lvl == 2) ? 0.25f : 0.125f;
                const float cxl = cx * inv, cyl = cy * inv;
                const float bxf = floorf(cxl), byf = floorf(cyl);
                const int bx = (int)bxf, by = (int)byf;
                const int gx = bx - 3 + p;
                const int gxc = min(max(gx, 0), wl - 1);
                const bool colv = (gx >= 0) & (gx < wl);

                uint4 u0[8], u1[8];
                if (lvl >= 2) {              // LDS-resident levels (swizzled)
                    const int baseRow = (lvl == 3) ? ROW_L3 : 0;
                    #pragma unroll
                    for (int j = 0; j < 8; ++j) {
                        const int gy = by - 3 + j;
                        const int gyc = min(max(gy, 0), hl - 1);
                        const int R = baseRow + gyc * wl + gxc;
                        const unsigned ro = ((unsigned)R << 8)
                                          | ((unsigned)(ch ^ (R & 7)) << 4);
                        u0[j] = *(const uint4*)(lds2 + ro);
                        u1[j] = *(const uint4*)(lds2 + ro + 128);
                    }
                } else {                     // global gather levels
                    const unsigned gbase = lvl ? gB1 : gB0;
                    const unsigned coloff = gbase + (unsigned)gxc * 256 + (unsigned)ch * 16;
                    #pragma unroll
                    for (int j = 0; j < 8; ++j) {
                        const int gy = by - 3 + j;
                        const int gyc = min(max(gy, 0), hl - 1);
                        const unsigned ro = coloff + (unsigned)(gyc * wl) * 256;
                        u0[j] = *(const uint4*)(ws + ro);
                        u1[j] = *(const uint4*)(ws + ro + 128);
                    }
                }

                float dval = 0.0f;
                #pragma unroll
                for (int j = 0; j < 8; ++j) {
                    float acc = dot_u4(u0[j], su0, 0.0f) + dot_u4(u1[j], su1, 0.0f);
                    acc = dpp_add<0xB1>(acc);    // quad_perm xor1
                    acc = dpp_add<0x4E>(acc);    // quad_perm xor2
                    acc = dpp_add<0x141>(acc);   // ROW_HALF_MIRROR (xor4 here)
                    dval = (ch == j) ? acc : dval;
                }
                const int gyo = by - 3 + ch;
                dval = (colv & (gyo >= 0) & (gyo < hl)) ? dval : 0.0f;

                // bilinear: tap (row,col) lives in lane 8*col+row
                const int dyi = L / 7, dxi = L - dyi * 7;
                const float fx = cxl - bxf, fy = cyl - byf;
                const float d00 = __shfl(dval, 8 * dxi + dyi);
                const float d01 = __shfl(dval, 8 * dxi + dyi + 8);
                const float d10 = __shfl(dval, 8 * dxi + dyi + 1);
                const float d11 = __shfl(dval, 8 * dxi + dyi + 9);
                vals[ps][lvl] = (d00 * (1.0f - fx) + d01 * fx) * (1.0f - fy) +
                                (d10 * (1.0f - fx) + d11 * fx) * fy;
            }
        }
    }

    __syncthreads();             // ALL gathers (incl. LDS lvl2/3 reads) done

    // reuse dead staged region as so[196][53] (41552 B < 126976 B)
    float* so = (float*)lds2;
    if (L < 49) {
        #pragma unroll
        for (int ps = 0; ps < 4; ++ps) {
            const int lpix = ps * 16 + wv;
            if (lpix < npix) {
                #pragma unroll
                for (int lvl = 0; lvl < 4; ++lvl)
                    so[(lvl * 49 + L) * 53 + lpix] = vals[ps][lvl];
            }
        }
    }

    __syncthreads();

    // coalesced write-out: 196 channels x npix floats
    for (int idx = t; idx < 196 * npix; idx += 1024) {
        const int chn = idx / npix;
        const int px  = idx - chn * npix;
        out[(size_t)(dir * 196 + chn) * HW_ + rbeg + px] = so[chn * 53 + px];
    }
    if (dir == 0) {
        for (int idx = t; idx < 4 * npix; idx += 1024) {
            const int c  = idx / npix;
            const int px = idx - c * npix;
            const float* f = (c < 2) ? flow0 + (size_t)c * HW_
                                     : flow1 + (size_t)(c - 2) * HW_;
            out[(size_t)(392 + c) * HW_ + rbeg + px] = f[rbeg + px];
        }
    }
}

// ---------------------------------------------------------------------------
extern "C" void kernel_launch(void* const* d_in, const int* in_sizes, int n_in,
                              void* d_out, int out_size, void* d_ws, size_t ws_size,
                              hipStream_t stream) {
    const float* fmap0 = (const float*)d_in[0];
    const float* fmap1 = (const float*)d_in[1];
    const float* flow0 = (const float*)d_in[2];
    const float* flow1 = (const float*)d_in[3];
    const float* embt  = (const float*)d_in[4];
    h16* ws  = (h16*)d_ws;
    float* out = (float*)d_out;

    (void)hipFuncSetAttribute((const void*)k_lookup4,
                              hipFuncAttributeMaxDynamicSharedMemorySize, LDS_TOT);

    k_transpose<<<dim3(102, 2), 256, 0, stream>>>(fmap0, fmap1, ws);
    k_pyramid<<<dim3(174, 2), 256, 0, stream>>>(ws);
    k_lookup4<<<dim3(256), 1024, LDS_TOT, stream>>>(ws, flow0, flow1, embt, out);
}

// Round 15
// 43.367 us; speedup vs baseline: 1.0049x; 1.0049x over previous
//
#include <hip/hip_runtime.h>

typedef _Float16 h16;
typedef __attribute__((ext_vector_type(2))) h16 h2v;
typedef __attribute__((ext_vector_type(8))) h16 h8v;

constexpr int H_ = 60, W_ = 108, HW_ = 6480;

// Workspace byte offsets. Features position-major [pos][128] fp16 (256 B/row).
// All features pre-scaled by 128^-0.25 so every dot carries 1/sqrt(128).
constexpr unsigned B_F0T  = 0;
constexpr unsigned B_F1T  = 1658880;
constexpr unsigned B_F0L1 = 3317760;   // 30*54
constexpr unsigned B_F0L2 = 3732480;   // 15*27
constexpr unsigned B_F0L3 = 3836160;   // 7*13
constexpr unsigned B_F1L1 = 3859456;
constexpr unsigned B_F1L2 = 4274176;
constexpr unsigned B_F1L3 = 4377856;

// ---------------------------------------------------------------------------
// Fused transpose + full pyramid. One block per 8x8 pixel tile (grid 14x8 x
// 2 maps). Stage tile in LDS (f16, pre-scaled), write L0 position-major,
// then compute L1 (2x2), L2 (4x4 direct), L3 (8x8 direct) from LDS.
// Containment: with 8x8 tiles, every L1/L2/L3 output lies inside one tile.
__global__ __launch_bounds__(256) void k_prep(const float* __restrict__ f0,
                                              const float* __restrict__ f1,
                                              h16* __restrict__ wsh) {
    __shared__ h16 tile[64 * 136];   // 272B row stride: 16B-aligned rows
    char* ws = (char*)wsh;
    const int map = blockIdx.y;
    const float* src = map ? f1 : f0;
    const unsigned oL0 = map ? B_F1T  : B_F0T;
    const unsigned oL1 = map ? B_F1L1 : B_F0L1;
    const unsigned oL2 = map ? B_F1L2 : B_F0L2;
    const unsigned oL3 = map ? B_F1L3 : B_F0L3;
    const int tx = blockIdx.x % 14, ty = blockIdx.x / 14;
    const int x0 = tx * 8, y0 = ty * 8;
    const int tw = min(8, 108 - x0), th = min(8, 60 - y0);   // 8 or 4
    const int t = threadIdx.x;
    const float S = 0.29730177875068026f;   // 128^-0.25

    // stage: lane L = tile pos, c0 = t>>6 sweeps its 32 channels
    {
        const int L = t & 63, c0 = t >> 6;
        const int lx = L & 7, ly = L >> 3;
        const int gx = min(x0 + lx, 107), gy = min(y0 + ly, 59);  // clamp edges
        const int gpos = gy * 108 + gx;
        #pragma unroll
        for (int k = 0; k < 32; ++k) {
            const int c = c0 * 32 + k;
            tile[L * 136 + c] = (h16)(src[(size_t)c * 6480 + gpos] * S);
        }
    }
    __syncthreads();

    // L0 write-out: 64 pos x 16 chunks
    #pragma unroll
    for (int i = 0; i < 4; ++i) {
        const int u = t + i * 256;
        const int pos = u >> 4, q = u & 15;
        const int plx = pos & 7, ply = pos >> 3;
        if (plx < tw && ply < th) {
            h8v v = *(const h8v*)&tile[pos * 136 + q * 8];
            *(h8v*)(ws + oL0 + (unsigned)((y0 + ply) * 108 + x0 + plx) * 256 + q * 16) = v;
        }
    }
    // L1: up to 16 positions x 16 chunks (= 256 threads)
    {
        const int pos = t >> 4, q = t & 15;
        const int px = pos & 3, py = pos >> 2;
        if (px < (tw >> 1) && py < (th >> 1)) {
            float a[8] = {};
            #pragma unroll
            for (int dy = 0; dy < 2; ++dy)
                #pragma unroll
                for (int dx = 0; dx < 2; ++dx) {
                    h8v v = *(const h8v*)&tile[((2*py+dy)*8 + 2*px+dx) * 136 + q * 8];
                    #pragma unroll
                    for (int k = 0; k < 8; ++k) a[k] += (float)v[k];
                }
            h8v o;
            #pragma unroll
            for (int k = 0; k < 8; ++k) o[k] = (h16)(a[k] * 0.25f);
            *(h8v*)(ws + oL1 + (unsigned)((y0/2 + py) * 54 + x0/2 + px) * 256 + q * 16) = o;
        }
    }
    // L2: up to 4 positions x 16 chunks
    if (t < 64) {
        const int pos = t >> 4, q = t & 15;
        const int px = pos & 1, py = pos >> 1;
        if (px < (tw >> 2) && py < (th >> 2)) {
            float a[8] = {};
            #pragma unroll
            for (int dy = 0; dy < 4; ++dy)
                #pragma unroll
                for (int dx = 0; dx < 4; ++dx) {
                    h8v v = *(const h8v*)&tile[((4*py+dy)*8 + 4*px+dx) * 136 + q * 8];
                    #pragma unroll
                    for (int k = 0; k < 8; ++k) a[k] += (float)v[k];
                }
            h8v o;
            #pragma unroll
            for (int k = 0; k < 8; ++k) o[k] = (h16)(a[k] * 0.0625f);
            *(h8v*)(ws + oL2 + (unsigned)((y0/4 + py) * 27 + x0/4 + px) * 256 + q * 16) = o;
        }
    }
    // L3: 1 position x 16 chunks (full tiles only: tx<13, ty<7 -> 91 pos)
    if (t < 16 && tx < 13 && ty < 7) {
        const int q = t;
        float a[8] = {};
        for (int pos = 0; pos < 64; ++pos) {
            h8v v = *(const h8v*)&tile[pos * 136 + q * 8];
            #pragma unroll
            for (int k = 0; k < 8; ++k) a[k] += (float)v[k];
        }
        h8v o;
        #pragma unroll
        for (int k = 0; k < 8; ++k) o[k] = (h16)(a[k] * 0.015625f);
        *(h8v*)(ws + oL3 + (unsigned)(ty * 13 + tx) * 256 + q * 16) = o;
    }
}

// ---------------------------------------------------------------------------
template <int CTRL>
__device__ __forceinline__ float dpp_add(float x) {
    int y = __builtin_amdgcn_update_dpp(0, __builtin_bit_cast(int, x),
                                        CTRL, 0xF, 0xF, true);
    return x + __builtin_bit_cast(float, y);
}

__device__ __forceinline__ float dot_u4(uint4 u, uint4 s, float acc) {
    acc = __builtin_amdgcn_fdot2(__builtin_bit_cast(h2v, u.x),
                                 __builtin_bit_cast(h2v, s.x), acc, false);
    acc = __builtin_amdgcn_fdot2(__builtin_bit_cast(h2v, u.y),
                                 __builtin_bit_cast(h2v, s.y), acc, false);
    acc = __builtin_amdgcn_fdot2(__builtin_bit_cast(h2v, u.z),
                                 __builtin_bit_cast(h2v, s.z), acc, false);
    acc = __builtin_amdgcn_fdot2(__builtin_bit_cast(h2v, u.w),
                                 __builtin_bit_cast(h2v, s.w), acc, false);
    return acc;
}

// R7-exact lookup (42.06us best): one WAVE per (pixel, dir); block = 4
// consecutive pixels. Lane L = (col p = L>>3, chunk ch = L&7): two contiguous
// 16B chunks per 256B row -> each load instr covers 1KB dense. Level 3 staged
// in LDS per block. DPP row-reduce; LDS-staged coalesced output.
__global__ __launch_bounds__(256, 4) void k_lookup(const h16* __restrict__ wsh,
                                                   const float* __restrict__ flow0,
                                                   const float* __restrict__ flow1,
                                                   const float* __restrict__ embt,
                                                   float* __restrict__ out) {
    __shared__ float so[196][5];          // [channel][pixel], +1 pad
    __shared__ char l3cache[91 * 256];    // whole level-3 of this dir (23.3 KB)
    const char* ws = (const char*)wsh;
    const int bid = blockIdx.x;
    const int xcd = bid & 7;
    const int dir = xcd >> 2;                      // XCDs 0-3: dir0, 4-7: dir1
    const int ord = (xcd & 3) * 405 + (bid >> 3);  // contiguous chunk per XCD
    const int pix0 = ord * 4;
    const int t = threadIdx.x;
    const int L = t & 63;
    const int pix = pix0 + (t >> 6);
    const int h = pix / 108, w = pix - h * 108;

    // stage level-3 (coalesced; 1456 x 16B chunks over 256 threads)
    {
        const char* l3src = ws + (dir ? B_F0L3 : B_F1L3);
        #pragma unroll
        for (int i = 0; i < 6; ++i) {
            const int c = t + i * 256;
            if (c < 91 * 16)
                ((uint4*)l3cache)[c] = *(const uint4*)(l3src + c * 16);
        }
    }

    const float e = embt[0];
    const float scale = dir ? 1.0f / (1.0f - e) : 1.0f / e;
    const float* fl = dir ? flow0 : flow1;
    const float cx = (float)w + fl[pix] * scale;
    const float cy = (float)h + fl[HW_ + pix] * scale;

    const int ch = L & 7;        // 16B chunk index
    const int p  = L >> 3;       // window column 0..7

    // source feature chunks (already scaled by 128^-0.25 at prep)
    const unsigned sbase = (dir ? B_F1T : B_F0T) + (unsigned)pix * 256;
    const uint4 su0 = *(const uint4*)(ws + sbase + ch * 16);
    const uint4 su1 = *(const uint4*)(ws + sbase + 128 + ch * 16);

    constexpr unsigned g0[4] = {B_F1T, B_F1L1, B_F1L2, B_F1L3};
    constexpr unsigned g1[4] = {B_F0T, B_F0L1, B_F0L2, B_F0L3};

    __syncthreads();   // l3cache ready

    #pragma unroll
    for (int lvl = 0; lvl < 4; ++lvl) {
        const unsigned gbase = dir ? g1[lvl] : g0[lvl];
        const int wl = 108 >> lvl, hl = 60 >> lvl;
        const float inv = (lvl == 0) ? 1.f : (lvl == 1) ? 0.5f : (lvl == 2) ? 0.25f : 0.125f;
        const float cxl = cx * inv, cyl = cy * inv;
        const float bxf = floorf(cxl), byf = floorf(cyl);
        const int bx = (int)bxf, by = (int)byf;
        const int gx = bx - 3 + p;
        const int gxc = min(max(gx, 0), wl - 1);
        const bool colv = (gx >= 0) & (gx < wl);
        const int gyo = by - 3 + ch;                 // row this lane keeps
        const bool ownv = colv & (gyo >= 0) & (gyo < hl);

        uint4 u0[8], u1[8];
        if (lvl == 3) {                  // LDS path (whole level cached)
            const unsigned co = (unsigned)gxc * 256 + (unsigned)ch * 16;
            #pragma unroll
            for (int j = 0; j < 8; ++j) {
                const int gy = by - 3 + j;
                const int gyc = min(max(gy, 0), hl - 1);
                const unsigned ro = co + (unsigned)(gyc * wl) * 256;
                u0[j] = *(const uint4*)(l3cache + ro);
                u1[j] = *(const uint4*)(l3cache + ro + 128);
            }
        } else {                         // global path
            const unsigned coloff = gbase + (unsigned)gxc * 256 + (unsigned)ch * 16;
            #pragma unroll
            for (int j = 0; j < 8; ++j) {
                const int gy = by - 3 + j;
                const int gyc = min(max(gy, 0), hl - 1);
                const unsigned ro = coloff + (unsigned)(gyc * wl) * 256;
                u0[j] = *(const uint4*)(ws + ro);
                u1[j] = *(const uint4*)(ws + ro + 128);
            }
        }

        float dval = 0.0f;
        #pragma unroll
        for (int j = 0; j < 8; ++j) {
            float a0 = dot_u4(u0[j], su0, 0.0f);
            float a1 = dot_u4(u1[j], su1, 0.0f);
            float acc = a0 + a1;
            acc = dpp_add<0xB1>(acc);    // quad_perm xor1
            acc = dpp_add<0x4E>(acc);    // quad_perm xor2
            acc = dpp_add<0x141>(acc);   // ROW_HALF_MIRROR (4-group-uniform => xor4)
            dval = (ch == j) ? acc : dval;
        }
        dval = ownv ? dval : 0.0f;

        // bilinear: output (dyi,dxi) for L<49; tap (row,col) lives in lane 8*col+row
        const int dyi = L / 7, dxi = L - dyi * 7;
        const float fx = cxl - bxf, fy = cyl - byf;
        const float d00 = __shfl(dval, 8 * dxi + dyi);
        const float d01 = __shfl(dval, 8 * dxi + dyi + 8);
        const float d10 = __shfl(dval, 8 * dxi + dyi + 1);
        const float d11 = __shfl(dval, 8 * dxi + dyi + 9);
        const float v = (d00 * (1.0f - fx) + d01 * fx) * (1.0f - fy) +
                        (d10 * (1.0f - fx) + d11 * fx) * fy;
        if (L < 49) so[lvl * 49 + L][t >> 6] = v;
    }
    __syncthreads();

    if (t < 196) {
        float4 o = make_float4(so[t][0], so[t][1], so[t][2], so[t][3]);
        *(float4*)(out + (size_t)(dir * 196 + t) * HW_ + pix0) = o;
    } else if (dir == 0 && t < 200) {
        const int c = t - 196;
        const float* f = (c < 2) ? flow0 + (size_t)c * HW_
                                 : flow1 + (size_t)(c - 2) * HW_;
        *(float4*)(out + (size_t)(392 + c) * HW_ + pix0) = *(const float4*)(f + pix0);
    }
}

// ---------------------------------------------------------------------------
extern "C" void kernel_launch(void* const* d_in, const int* in_sizes, int n_in,
                              void* d_out, int out_size, void* d_ws, size_t ws_size,
                              hipStream_t stream) {
    const float* fmap0 = (const float*)d_in[0];
    const float* fmap1 = (const float*)d_in[1];
    const float* flow0 = (const float*)d_in[2];
    const float* flow1 = (const float*)d_in[3];
    const float* embt  = (const float*)d_in[4];
    h16* ws  = (h16*)d_ws;
    float* out = (float*)d_out;

    k_prep<<<dim3(112, 2), 256, 0, stream>>>(fmap0, fmap1, ws);
    k_lookup<<<dim3(405 * 8), 256, 0, stream>>>(ws, flow0, flow1, embt, out);
}